// Round 1
// baseline (28880.356 us; speedup 1.0000x reference)
//
#include <hip/hip_runtime.h>

// Problem constants
#define Bq 256
#define Tq 2048
#define Fq 64
#define Hq 512
#define Cq 128
#define KSTEPS 18          // K = F + H = 576, 18 k-steps of 32
#define LDK 600            // padded LDS row stride in bf16 elements (2-way-max bank aliasing)
#define BMq 32             // batch rows per workgroup

typedef __attribute__((ext_vector_type(8))) short bf16x8;
typedef __attribute__((ext_vector_type(4))) float f32x4;

__device__ __forceinline__ unsigned short f2bf(float f) {
  unsigned u = __float_as_uint(f);
  return (unsigned short)((u + 0x7fffu + ((u >> 16) & 1u)) >> 16);  // RNE
}
__device__ __forceinline__ unsigned pack2bf(float lo, float hi) {
  return (unsigned)f2bf(lo) | ((unsigned)f2bf(hi) << 16);
}
// packed relu on 2x bf16 in a dword: zero halves whose sign bit is set
__device__ __forceinline__ unsigned relu2(unsigned v) {
  unsigned m = (v >> 15) & 0x00010001u;
  return v & ~(m * 0xFFFFu);
}
__device__ __forceinline__ float sigmf(float x) { return 1.f / (1.f + __expf(-x)); }
__device__ __forceinline__ float tanhf_(float x) {
  float e = __expf(-2.f * fabsf(x));      // e in (0,1], no inf/NaN path
  float t = (1.f - e) / (1.f + e);
  return copysignf(t, x);
}

__global__ __launch_bounds__(256, 1)
void lstm_persistent(const float* __restrict__ x,
                     const float* __restrict__ W_ih,
                     const float* __restrict__ W_hh,
                     const float* __restrict__ b_ih,
                     const float* __restrict__ b_hh,
                     const float* __restrict__ W_d,
                     const float* __restrict__ b_d,
                     float* __restrict__ out,
                     unsigned* __restrict__ cnt_base,
                     unsigned* __restrict__ hbuf) {
  __shared__ __align__(16) unsigned short xh[BMq * LDK];   // [32 x 600] bf16 = 37.5 KB
  __shared__ float gexch[4][BMq][17];                      // gate exchange, 8.5 KB
  __shared__ float cstate[BMq][17];                        // fp32 cell state, 2.1 KB
  __shared__ float proj[4][16][17];                        // projection partials, 4.25 KB

  const int tid  = threadIdx.x;
  const int wave = tid >> 6;        // 4 waves = the 4 gates (i,f,g,o)
  const int lane = tid & 63;
  const int l15  = lane & 15;
  const int quad = lane >> 4;
  const int bm = blockIdx.x & 7;    // XCD-colocated batch group (blockIdx%8 -> XCD)
  const int cn = blockIdx.x >> 3;   // hidden-unit tile, 16 units each

  // ---- persistent W fragments (B-operand): W row = gate*512 + cn*16 + l15
  bf16x8 wfrag[KSTEPS];
  const int gcol = wave * Hq + cn * 16 + l15;
  #pragma unroll
  for (int s = 0; s < KSTEPS; ++s) {
    int k = s * 32 + quad * 8;
    const float* src = (k < Fq) ? (W_ih + (long)gcol * Fq + k)
                                : (W_hh + (long)gcol * Hq + (k - Fq));
    float4 a = *(const float4*)src;
    float4 b = *(const float4*)(src + 4);
    union { unsigned short s_[8]; bf16x8 v; } u;
    u.s_[0] = f2bf(a.x); u.s_[1] = f2bf(a.y); u.s_[2] = f2bf(a.z); u.s_[3] = f2bf(a.w);
    u.s_[4] = f2bf(b.x); u.s_[5] = f2bf(b.y); u.s_[6] = f2bf(b.z); u.s_[7] = f2bf(b.w);
    wfrag[s] = u.v;
  }
  const float bias = b_ih[gcol] + b_hh[gcol];

  // ---- projection setup (wgs cn<16: tile [16 batch x 16 out-cols], K split 4 ways over waves)
  const bool projwg = (cn < 16);
  const int rt2 = cn & 1, ct = cn >> 1;
  bf16x8 wdfrag[4];
  float bdred = 0.f;
  if (projwg) {
    const int pcol = ct * 16 + l15;
    #pragma unroll
    for (int q = 0; q < 4; ++q) {
      int k = (wave * 4 + q) * 32 + quad * 8;
      const float* src = W_d + (long)pcol * Hq + k;
      float4 a = *(const float4*)src;
      float4 b = *(const float4*)(src + 4);
      union { unsigned short s_[8]; bf16x8 v; } u;
      u.s_[0] = f2bf(a.x); u.s_[1] = f2bf(a.y); u.s_[2] = f2bf(a.z); u.s_[3] = f2bf(a.w);
      u.s_[4] = f2bf(b.x); u.s_[5] = f2bf(b.y); u.s_[6] = f2bf(b.z); u.s_[7] = f2bf(b.w);
      wdfrag[q] = u.v;
    }
    bdred = b_d[ct * 16 + (tid & 15)];
  }

  for (int i = tid; i < BMq * 17; i += 256) ((float*)cstate)[i] = 0.f;

  unsigned* cnt = cnt_base + bm * 32;                       // own 128B line per group
  unsigned* slot0 = hbuf;
  unsigned* slot1 = hbuf + (Bq * Hq / 2);

  for (int t = 0; t <= Tq; ++t) {
    // ---- group barrier: wait until all 32 wgs of group wrote h_{t-1}
    if (t > 0 && tid == 0) {
      const unsigned target = (unsigned)t * 32u;
      while (__hip_atomic_load(cnt, __ATOMIC_RELAXED, __HIP_MEMORY_SCOPE_AGENT) < target)
        __builtin_amdgcn_s_sleep(1);
    }
    __syncthreads();

    // ---- stage x_t (bf16) into xh[:, 0:64]
    if (t < Tq) {
      #pragma unroll
      for (int j = 0; j < 4; ++j) {
        int p = j * 256 + tid;
        int row = p >> 5;
        int fp = (p & 31) * 2;
        const float* src = x + ((long)(bm * BMq + row) * Tq + t) * Fq + fp;
        float2 v = *(const float2*)src;
        *(unsigned*)&xh[row * LDK + fp] = pack2bf(v.x, v.y);
      }
    }
    // ---- stage h_{t-1} into xh[:, 64:576] (agent-scope loads: LLC-coherent, L2-bypass)
    if (t == 0) {
      #pragma unroll
      for (int j = 0; j < 32; ++j) {
        int idx = j * 256 + tid;
        *(unsigned*)&xh[(idx >> 8) * LDK + Fq + (idx & 255) * 2] = 0u;
      }
    } else {
      unsigned* hsrc = ((t - 1) & 1 ? slot1 : slot0) + (long)bm * BMq * (Hq / 2);
      #pragma unroll
      for (int j = 0; j < 32; ++j) {
        int idx = j * 256 + tid;
        unsigned v = __hip_atomic_load(hsrc + (idx >> 8) * (Hq / 2) + (idx & 255),
                                       __ATOMIC_RELAXED, __HIP_MEMORY_SCOPE_AGENT);
        *(unsigned*)&xh[(idx >> 8) * LDK + Fq + (idx & 255) * 2] = v;
      }
    }
    __syncthreads();

    // ---- gates GEMM: [32 x 16] per wave (its gate), K=576, W from registers
    if (t < Tq) {
      f32x4 acc0 = {0.f, 0.f, 0.f, 0.f}, acc1 = {0.f, 0.f, 0.f, 0.f};
      #pragma unroll
      for (int s = 0; s < KSTEPS; ++s) {
        const int ko = s * 32 + quad * 8;
        bf16x8 a0 = *(const bf16x8*)&xh[l15 * LDK + ko];
        bf16x8 a1 = *(const bf16x8*)&xh[(16 + l15) * LDK + ko];
        acc0 = __builtin_amdgcn_mfma_f32_16x16x32_bf16(a0, wfrag[s], acc0, 0, 0, 0);
        acc1 = __builtin_amdgcn_mfma_f32_16x16x32_bf16(a1, wfrag[s], acc1, 0, 0, 0);
      }
      #pragma unroll
      for (int r = 0; r < 4; ++r) {
        gexch[wave][quad * 4 + r][l15]      = acc0[r] + bias;
        gexch[wave][16 + quad * 4 + r][l15] = acc1[r] + bias;
      }
    }

    // ---- projection MFMA for logits_{t-1}: relu(h_{t-1}) @ W_d^T, partial K per wave
    if (t > 0 && projwg) {
      f32x4 pacc = {0.f, 0.f, 0.f, 0.f};
      #pragma unroll
      for (int q = 0; q < 4; ++q) {
        const int k = (wave * 4 + q) * 32 + quad * 8;
        const unsigned* ap = (const unsigned*)&xh[(rt2 * 16 + l15) * LDK + Fq + k];
        union { unsigned u[4]; bf16x8 v; } cv;
        cv.u[0] = relu2(ap[0]); cv.u[1] = relu2(ap[1]);
        cv.u[2] = relu2(ap[2]); cv.u[3] = relu2(ap[3]);
        pacc = __builtin_amdgcn_mfma_f32_16x16x32_bf16(cv.v, wdfrag[q], pacc, 0, 0, 0);
      }
      #pragma unroll
      for (int r = 0; r < 4; ++r) proj[wave][quad * 4 + r][l15] = pacc[r];
    }
    __syncthreads();

    // ---- cell update (fp32 state in LDS), write h_t bf16 to ring slot
    if (t < Tq) {
      const int row = tid >> 3;
      const int cp = tid & 7;
      float hv[2];
      #pragma unroll
      for (int e = 0; e < 2; ++e) {
        const int col = cp * 2 + e;
        float ig = sigmf(gexch[0][row][col]);
        float fg = sigmf(gexch[1][row][col]);
        float gg = tanhf_(gexch[2][row][col]);
        float og = sigmf(gexch[3][row][col]);
        float cv = fg * cstate[row][col] + ig * gg;
        cstate[row][col] = cv;
        hv[e] = og * tanhf_(cv);
      }
      unsigned hp = pack2bf(hv[0], hv[1]);
      unsigned* dst = ((t & 1) ? slot1 : slot0)
                    + (long)(bm * BMq + row) * (Hq / 2) + cn * 8 + cp;
      __hip_atomic_store(dst, hp, __ATOMIC_RELAXED, __HIP_MEMORY_SCOPE_AGENT);
    }

    // ---- projection reduce (4 K-partials) + bias, store logits to d_out
    if (t > 0 && projwg) {
      const int row = tid >> 4, col = tid & 15;
      float z = proj[0][row][col] + proj[1][row][col]
              + proj[2][row][col] + proj[3][row][col] + bdred;
      const long b = bm * BMq + rt2 * 16 + row;
      out[b * (long)(Tq * Cq) + (long)(t - 1) * Cq + ct * 16 + col] = z;
    }

    // ---- signal h_t complete
    if (t < Tq) {
      __syncthreads();   // drains all threads' h stores (vmcnt(0) before s_barrier)
      if (tid == 0)
        __hip_atomic_fetch_add(cnt, 1u, __ATOMIC_RELEASE, __HIP_MEMORY_SCOPE_AGENT);
    }
  }
}

// In-place softmax over the 128-wide rows of d_out; one wave per row.
__global__ __launch_bounds__(256)
void softmax_rows(float* __restrict__ out) {
  const long row = ((long)blockIdx.x * blockDim.x + threadIdx.x) >> 6;
  const int lane = threadIdx.x & 63;
  float* p = out + row * Cq + lane * 2;
  float2 v = *(const float2*)p;
  float m = fmaxf(v.x, v.y);
  #pragma unroll
  for (int off = 32; off > 0; off >>= 1) m = fmaxf(m, __shfl_down(m, off));
  m = __shfl(m, 0);
  float e0 = __expf(v.x - m), e1 = __expf(v.y - m);
  float s = e0 + e1;
  #pragma unroll
  for (int off = 32; off > 0; off >>= 1) s += __shfl_down(s, off);
  s = __shfl(s, 0);
  float inv = 1.f / s;
  float2 r; r.x = e0 * inv; r.y = e1 * inv;
  *(float2*)p = r;
}

extern "C" void kernel_launch(void* const* d_in, const int* in_sizes, int n_in,
                              void* d_out, int out_size, void* d_ws, size_t ws_size,
                              hipStream_t stream) {
  const float* x    = (const float*)d_in[0];
  const float* W_ih = (const float*)d_in[1];
  const float* W_hh = (const float*)d_in[2];
  const float* b_ih = (const float*)d_in[3];
  const float* b_hh = (const float*)d_in[4];
  const float* W_d  = (const float*)d_in[5];
  const float* b_d  = (const float*)d_in[6];
  float* out = (float*)d_out;

  // ws layout: [0,4096) group barrier counters; [4096, 4096+512KB) h ring (2 slots bf16)
  unsigned* cnt  = (unsigned*)d_ws;
  unsigned* hbuf = (unsigned*)((char*)d_ws + 4096);

  hipMemsetAsync(d_ws, 0, 4096, stream);  // zero barrier counters (ws is poisoned 0xAA)

  hipLaunchKernelGGL(lstm_persistent, dim3(256), dim3(256), 0, stream,
                     x, W_ih, W_hh, b_ih, b_hh, W_d, b_d, out, cnt, hbuf);

  // softmax: B*T rows, 4 rows (waves) per 256-thread block
  hipLaunchKernelGGL(softmax_rows, dim3((Bq * Tq) / 4), dim3(256), 0, stream, out);
}

// Round 2
// 20797.273 us; speedup vs baseline: 1.3887x; 1.3887x over previous
//
#include <hip/hip_runtime.h>

// Problem constants
#define Bq 256
#define Tq 2048
#define Fq 64
#define Hq 512
#define Cq 128
#define KSTEPS 18          // K = F + H = 576, 18 k-steps of 32
#define LDK 600            // padded LDS row stride in bf16 elements
#define BMq 32             // batch rows per workgroup

typedef __attribute__((ext_vector_type(8))) short bf16x8;
typedef __attribute__((ext_vector_type(4))) float f32x4;

__device__ __forceinline__ unsigned short f2bf(float f) {
  unsigned u = __float_as_uint(f);
  return (unsigned short)((u + 0x7fffu + ((u >> 16) & 1u)) >> 16);  // RNE
}
__device__ __forceinline__ unsigned pack2bf(float lo, float hi) {
  return (unsigned)f2bf(lo) | ((unsigned)f2bf(hi) << 16);
}
// packed relu on 2x bf16 in a dword: zero halves whose sign bit is set
__device__ __forceinline__ unsigned relu2(unsigned v) {
  unsigned m = (v >> 15) & 0x00010001u;
  return v & ~(m * 0xFFFFu);
}
__device__ __forceinline__ float sigmf(float x) { return 1.f / (1.f + __expf(-x)); }
__device__ __forceinline__ float tanhf_(float x) {
  float e = __expf(-2.f * fabsf(x));      // e in (0,1], no inf/NaN path
  float t = (1.f - e) / (1.f + e);
  return copysignf(t, x);
}

__global__ __launch_bounds__(256, 1)
void lstm_persistent(const float* __restrict__ x,
                     const float* __restrict__ W_ih,
                     const float* __restrict__ W_hh,
                     const float* __restrict__ b_ih,
                     const float* __restrict__ b_hh,
                     const float* __restrict__ W_d,
                     const float* __restrict__ b_d,
                     float* __restrict__ out,
                     unsigned* __restrict__ cnt_base,
                     unsigned* __restrict__ hbuf) {
  __shared__ __align__(16) unsigned short xh[BMq * LDK];   // [32 x 600] bf16 = 37.5 KB
  __shared__ float gexch[4][BMq][17];                      // gate exchange, 8.5 KB
  __shared__ float cstate[BMq][17];                        // fp32 cell state, 2.1 KB
  __shared__ float proj[4][16][17];                        // projection partials, 4.25 KB

  const int tid  = threadIdx.x;
  const int wave = tid >> 6;        // 4 waves = the 4 gates (i,f,g,o)
  const int lane = tid & 63;
  const int l15  = lane & 15;
  const int quad = lane >> 4;
  const int bm = blockIdx.x & 7;    // XCD-colocated batch group (blockIdx%8 -> XCD)
  const int cn = blockIdx.x >> 3;   // hidden-unit tile, 16 units each

  // ---- persistent W fragments (B-operand): W row = gate*512 + cn*16 + l15
  bf16x8 wfrag[KSTEPS];
  const int gcol = wave * Hq + cn * 16 + l15;
  #pragma unroll
  for (int s = 0; s < KSTEPS; ++s) {
    int k = s * 32 + quad * 8;
    const float* src = (k < Fq) ? (W_ih + (long)gcol * Fq + k)
                                : (W_hh + (long)gcol * Hq + (k - Fq));
    float4 a = *(const float4*)src;
    float4 b = *(const float4*)(src + 4);
    union { unsigned short s_[8]; bf16x8 v; } u;
    u.s_[0] = f2bf(a.x); u.s_[1] = f2bf(a.y); u.s_[2] = f2bf(a.z); u.s_[3] = f2bf(a.w);
    u.s_[4] = f2bf(b.x); u.s_[5] = f2bf(b.y); u.s_[6] = f2bf(b.z); u.s_[7] = f2bf(b.w);
    wfrag[s] = u.v;
  }
  const float bias = b_ih[gcol] + b_hh[gcol];

  // ---- projection setup (wgs cn<16: tile [16 batch x 16 out-cols], K split 4 ways over waves)
  const bool projwg = (cn < 16);
  const int rt2 = cn & 1, ct = cn >> 1;
  bf16x8 wdfrag[4];
  float bdred = 0.f;
  if (projwg) {
    const int pcol = ct * 16 + l15;
    #pragma unroll
    for (int q = 0; q < 4; ++q) {
      int k = (wave * 4 + q) * 32 + quad * 8;
      const float* src = W_d + (long)pcol * Hq + k;
      float4 a = *(const float4*)src;
      float4 b = *(const float4*)(src + 4);
      union { unsigned short s_[8]; bf16x8 v; } u;
      u.s_[0] = f2bf(a.x); u.s_[1] = f2bf(a.y); u.s_[2] = f2bf(a.z); u.s_[3] = f2bf(a.w);
      u.s_[4] = f2bf(b.x); u.s_[5] = f2bf(b.y); u.s_[6] = f2bf(b.z); u.s_[7] = f2bf(b.w);
      wdfrag[q] = u.v;
    }
    bdred = b_d[ct * 16 + (tid & 15)];
  }

  for (int i = tid; i < BMq * 17; i += 256) ((float*)cstate)[i] = 0.f;

  unsigned* cnt = cnt_base + bm * 32;                       // own 128B line per group
  unsigned* slot0 = hbuf;
  unsigned* slot1 = hbuf + (Bq * Hq / 2);

  // ---- prefetch x_0 into registers (packed bf16 pairs)
  unsigned xreg[4];
  {
    #pragma unroll
    for (int j = 0; j < 4; ++j) {
      int row = j * 8 + (tid >> 5);
      const float* src = x + ((long)(bm * BMq + row) * Tq + 0) * Fq + (tid & 31) * 2;
      float2 v = *(const float2*)src;
      xreg[j] = pack2bf(v.x, v.y);
    }
  }

  for (int t = 0; t <= Tq; ++t) {
    __syncthreads();   // sync1 — pairs with end-of-prev-iter poll

    // ---- phase A (off critical path): reduce proj partials for logits row t-2
    if (t >= 2 && projwg) {
      const int row = tid >> 4, col = tid & 15;
      float z = proj[0][row][col] + proj[1][row][col]
              + proj[2][row][col] + proj[3][row][col] + bdred;
      const long b = bm * BMq + rt2 * 16 + row;
      out[b * (long)(Tq * Cq) + (long)(t - 2) * Cq + ct * 16 + col] = z;
    }

    // ---- stage x_t (from prefetch regs) into xh[:, 0:64]
    if (t < Tq) {
      #pragma unroll
      for (int j = 0; j < 4; ++j) {
        int row = j * 8 + (tid >> 5);
        *(unsigned*)&xh[row * LDK + (tid & 31) * 2] = xreg[j];
      }
    }
    // ---- stage h_{t-1} into xh[:, 64:576] (agent-scope loads: LLC-coherent)
    if (t == 0) {
      #pragma unroll
      for (int j = 0; j < 32; ++j) {
        int idx = j * 256 + tid;
        *(unsigned*)&xh[(idx >> 8) * LDK + Fq + (idx & 255) * 2] = 0u;
      }
    } else {
      unsigned* hsrc = ((t - 1) & 1 ? slot1 : slot0) + (long)bm * BMq * (Hq / 2);
      #pragma unroll
      for (int j = 0; j < 32; ++j) {
        int idx = j * 256 + tid;
        unsigned v = __hip_atomic_load(hsrc + (idx >> 8) * (Hq / 2) + (idx & 255),
                                       __ATOMIC_RELAXED, __HIP_MEMORY_SCOPE_AGENT);
        *(unsigned*)&xh[(idx >> 8) * LDK + Fq + (idx & 255) * 2] = v;
      }
    }
    __syncthreads();   // sync2

    // ---- gates GEMM: [32 x 16] per wave (its gate), K=576, W from registers
    if (t < Tq) {
      f32x4 acc0 = {0.f, 0.f, 0.f, 0.f}, acc1 = {0.f, 0.f, 0.f, 0.f};
      #pragma unroll
      for (int s = 0; s < KSTEPS; ++s) {
        const int ko = s * 32 + quad * 8;
        bf16x8 a0 = *(const bf16x8*)&xh[l15 * LDK + ko];
        bf16x8 a1 = *(const bf16x8*)&xh[(16 + l15) * LDK + ko];
        acc0 = __builtin_amdgcn_mfma_f32_16x16x32_bf16(a0, wfrag[s], acc0, 0, 0, 0);
        acc1 = __builtin_amdgcn_mfma_f32_16x16x32_bf16(a1, wfrag[s], acc1, 0, 0, 0);
      }
      #pragma unroll
      for (int r = 0; r < 4; ++r) {
        gexch[wave][quad * 4 + r][l15]      = acc0[r] + bias;
        gexch[wave][16 + quad * 4 + r][l15] = acc1[r] + bias;
      }
      // ---- prefetch x_{t+1} (independent of h; overlaps barriers/cell update)
      if (t + 1 < Tq) {
        #pragma unroll
        for (int j = 0; j < 4; ++j) {
          int row = j * 8 + (tid >> 5);
          const float* src = x + ((long)(bm * BMq + row) * Tq + (t + 1)) * Fq + (tid & 31) * 2;
          float2 v = *(const float2*)src;
          xreg[j] = pack2bf(v.x, v.y);
        }
      }
    }
    __syncthreads();   // sync3

    // ---- cell update (fp32 state in LDS), write h_t bf16 to ring slot
    if (t < Tq) {
      const int row = tid >> 3;
      const int cp = tid & 7;
      float hv[2];
      #pragma unroll
      for (int e = 0; e < 2; ++e) {
        const int col = cp * 2 + e;
        float ig = sigmf(gexch[0][row][col]);
        float fg = sigmf(gexch[1][row][col]);
        float gg = tanhf_(gexch[2][row][col]);
        float og = sigmf(gexch[3][row][col]);
        float cv = fg * cstate[row][col] + ig * gg;
        cstate[row][col] = cv;
        hv[e] = og * tanhf_(cv);
      }
      unsigned hp = pack2bf(hv[0], hv[1]);
      unsigned* dst = ((t & 1) ? slot1 : slot0)
                    + (long)(bm * BMq + row) * (Hq / 2) + cn * 8 + cp;
      __hip_atomic_store(dst, hp, __ATOMIC_RELAXED, __HIP_MEMORY_SCOPE_AGENT);

      __syncthreads();   // sync4 — s_waitcnt vmcnt(0) drains all h stores (LLC-acked)
      // Relaxed add: ordering vs the h stores is provided by the vmcnt(0) drain
      // above + LLC serialization. RELEASE here would emit buffer_wbl2 (full
      // per-XCD L2 dirty writeback) every step — the 14us/step killer.
      __atomic_signal_fence(__ATOMIC_SEQ_CST);   // compiler-only: pin source order
      if (tid == 0)
        __hip_atomic_fetch_add(cnt, 1u, __ATOMIC_RELAXED, __HIP_MEMORY_SCOPE_AGENT);
    }

    // ---- projection MFMA for logits row t-1 (xh still holds h_{t-1});
    //      runs in the slack window while waiting for other wgs
    if (t >= 1 && projwg) {
      f32x4 pacc = {0.f, 0.f, 0.f, 0.f};
      #pragma unroll
      for (int q = 0; q < 4; ++q) {
        const int k = (wave * 4 + q) * 32 + quad * 8;
        const unsigned* ap = (const unsigned*)&xh[(rt2 * 16 + l15) * LDK + Fq + k];
        union { unsigned u[4]; bf16x8 v; } cv;
        cv.u[0] = relu2(ap[0]); cv.u[1] = relu2(ap[1]);
        cv.u[2] = relu2(ap[2]); cv.u[3] = relu2(ap[3]);
        pacc = __builtin_amdgcn_mfma_f32_16x16x32_bf16(cv.v, wdfrag[q], pacc, 0, 0, 0);
      }
      #pragma unroll
      for (int r = 0; r < 4; ++r) proj[wave][quad * 4 + r][l15] = pacc[r];
    }

    // ---- poll for h_t completion (needed before staging at iter t+1)
    if (t + 1 <= Tq && tid == 0) {
      const unsigned target = (unsigned)(t + 1) * 32u;
      __atomic_signal_fence(__ATOMIC_SEQ_CST);
      while (__hip_atomic_load(cnt, __ATOMIC_RELAXED, __HIP_MEMORY_SCOPE_AGENT) < target)
        __builtin_amdgcn_s_sleep(1);
    }
  }

  // ---- epilogue: reduce + store the last logits row (Tq-1)
  __syncthreads();
  if (projwg) {
    const int row = tid >> 4, col = tid & 15;
    float z = proj[0][row][col] + proj[1][row][col]
            + proj[2][row][col] + proj[3][row][col] + bdred;
    const long b = bm * BMq + rt2 * 16 + row;
    out[b * (long)(Tq * Cq) + (long)(Tq - 1) * Cq + ct * 16 + col] = z;
  }
}

// In-place softmax over the 128-wide rows of d_out; one wave per row.
__global__ __launch_bounds__(256)
void softmax_rows(float* __restrict__ out) {
  const long row = ((long)blockIdx.x * blockDim.x + threadIdx.x) >> 6;
  const int lane = threadIdx.x & 63;
  float* p = out + row * Cq + lane * 2;
  float2 v = *(const float2*)p;
  float m = fmaxf(v.x, v.y);
  #pragma unroll
  for (int off = 32; off > 0; off >>= 1) m = fmaxf(m, __shfl_down(m, off));
  m = __shfl(m, 0);
  float e0 = __expf(v.x - m), e1 = __expf(v.y - m);
  float s = e0 + e1;
  #pragma unroll
  for (int off = 32; off > 0; off >>= 1) s += __shfl_down(s, off);
  s = __shfl(s, 0);
  float inv = 1.f / s;
  float2 r; r.x = e0 * inv; r.y = e1 * inv;
  *(float2*)p = r;
}

extern "C" void kernel_launch(void* const* d_in, const int* in_sizes, int n_in,
                              void* d_out, int out_size, void* d_ws, size_t ws_size,
                              hipStream_t stream) {
  const float* x    = (const float*)d_in[0];
  const float* W_ih = (const float*)d_in[1];
  const float* W_hh = (const float*)d_in[2];
  const float* b_ih = (const float*)d_in[3];
  const float* b_hh = (const float*)d_in[4];
  const float* W_d  = (const float*)d_in[5];
  const float* b_d  = (const float*)d_in[6];
  float* out = (float*)d_out;

  // ws layout: [0,4096) group barrier counters; [4096, 4096+512KB) h ring (2 slots bf16)
  unsigned* cnt  = (unsigned*)d_ws;
  unsigned* hbuf = (unsigned*)((char*)d_ws + 4096);

  hipMemsetAsync(d_ws, 0, 4096, stream);  // zero barrier counters (ws is poisoned 0xAA)

  hipLaunchKernelGGL(lstm_persistent, dim3(256), dim3(256), 0, stream,
                     x, W_ih, W_hh, b_ih, b_hh, W_d, b_d, out, cnt, hbuf);

  // softmax: B*T rows, 4 rows (waves) per 256-thread block
  hipLaunchKernelGGL(softmax_rows, dim3((Bq * Tq) / 4), dim3(256), 0, stream, out);
}